// Round 1
// baseline (447.003 us; speedup 1.0000x reference)
//
#include <hip/hip_runtime.h>
#include <math.h>

#define B 8
#define T 128
#define S_ENC 400
#define H 256
#define V 50257

// ---------------------------------------------------------------------------
// Kernel 1: one block per (b,t). Computes:
//   p   = sigmoid(ctx.Wc + bc + dout.Wo + bo + din.Wi + bi)
//   lse = logsumexp over the copy_dist row (sparse: <=400 nonzeros,
//         remaining V-nnz entries are exactly 0 -> contribute exp(0))
// Writes params[bt] = (p, (1-p)*lse, (1-p), 0)
// ---------------------------------------------------------------------------
__global__ __launch_bounds__(256) void prep_kernel(
    const int*   __restrict__ tokens,   // [B,S]
    const float* __restrict__ context,  // [B,T,H]
    const float* __restrict__ dec_in,   // [B,T,H]
    const float* __restrict__ dec_out,  // [B,T,H]
    const float* __restrict__ attn,     // [B,T,S]
    const float* __restrict__ Wc, const float* __restrict__ bc,
    const float* __restrict__ Wo, const float* __restrict__ bo,
    const float* __restrict__ Wi, const float* __restrict__ bi,
    float4* __restrict__ params)        // [B*T]
{
    __shared__ int           tok_s[S_ENC];
    __shared__ float         acc[S_ENC];
    __shared__ unsigned char isf[S_ENC];
    __shared__ float s_pg[4];
    __shared__ float s_m[4];
    __shared__ int   s_n[4];
    __shared__ float s_se[4];
    __shared__ float s_mb;   // broadcast max

    const int bt   = blockIdx.x;
    const int b    = bt >> 7;            // T = 128
    const int tid  = threadIdx.x;
    const int lane = tid & 63;
    const int wave = tid >> 6;

    // load token row, zero accumulators
    for (int s = tid; s < S_ENC; s += 256) {
        tok_s[s] = tokens[b * S_ENC + s];
        acc[s]   = 0.0f;
    }
    __syncthreads();

    // p_gen partial: H == 256 == blockDim, one element per thread
    {
        float v = context[bt * H + tid] * Wc[tid]
                + dec_out[bt * H + tid] * Wo[tid]
                + dec_in [bt * H + tid] * Wi[tid];
        #pragma unroll
        for (int off = 32; off; off >>= 1) v += __shfl_down(v, off, 64);
        if (lane == 0) s_pg[wave] = v;
    }

    // duplicate-merge the scatter: first-occurrence representative per token
    for (int s = tid; s < S_ENC; s += 256) {
        int tk = tok_s[s];
        int f  = s;
        for (int j = 0; j < s; ++j) {
            if (tok_s[j] == tk) { f = j; break; }
        }
        isf[s] = (unsigned char)(f == s);
        atomicAdd(&acc[f], attn[bt * S_ENC + s]);
    }
    __syncthreads();

    // max + nnz over merged sparse values
    {
        float m = 0.0f;   // zero entries exist (V >> nnz) so max >= 0
        int   n = 0;
        for (int s = tid; s < S_ENC; s += 256) {
            if (isf[s]) { m = fmaxf(m, acc[s]); n++; }
        }
        #pragma unroll
        for (int off = 32; off; off >>= 1) {
            m  = fmaxf(m, __shfl_down(m, off, 64));
            n += __shfl_down(n, off, 64);
        }
        if (lane == 0) { s_m[wave] = m; s_n[wave] = n; }
    }
    __syncthreads();
    if (tid == 0) {
        s_mb = fmaxf(fmaxf(s_m[0], s_m[1]), fmaxf(s_m[2], s_m[3]));
    }
    __syncthreads();

    // sum of exp(acc - m) over sparse entries
    {
        const float m = s_mb;
        float se = 0.0f;
        for (int s = tid; s < S_ENC; s += 256) {
            if (isf[s]) se += expf(acc[s] - m);
        }
        #pragma unroll
        for (int off = 32; off; off >>= 1) se += __shfl_down(se, off, 64);
        if (lane == 0) s_se[wave] = se;
    }
    __syncthreads();

    if (tid == 0) {
        const float m   = s_mb;
        const int   nnz = s_n[0] + s_n[1] + s_n[2] + s_n[3];
        float se  = s_se[0] + s_se[1] + s_se[2] + s_se[3]
                  + (float)(V - nnz) * expf(-m);
        float lse = m + logf(se);
        float x   = s_pg[0] + s_pg[1] + s_pg[2] + s_pg[3]
                  + bc[0] + bo[0] + bi[0];
        float p   = 1.0f / (1.0f + expf(-x));
        float q   = 1.0f - p;
        params[bt] = make_float4(p, q * lse, q, 0.0f);
    }
}

// ---------------------------------------------------------------------------
// Kernel 2: streaming mix. out[e] = vocab[e]*p[bt] - (1-p[bt])*lse[bt]
// One float4 per thread; total elements divisible by 4 (V*B*T = 256*50257*4).
// Rows (length V, odd) can straddle a float4 -> boundary path per element.
// ---------------------------------------------------------------------------
__global__ __launch_bounds__(256) void mix_kernel(
    const float4* __restrict__ vocab,
    const float4* __restrict__ params,
    float4* __restrict__ out)
{
    const int idx = blockIdx.x * 256 + threadIdx.x;   // < B*T*V/4
    const int e   = idx * 4;
    const int bt  = e / V;                            // magic-mul (V constexpr)
    const int rem = e - bt * V;

    float4 v = vocab[idx];
    float4 o;
    if (rem + 4 <= V) {
        const float4 P = params[bt];
        o.x = v.x * P.x - P.y;
        o.y = v.y * P.x - P.y;
        o.z = v.z * P.x - P.y;
        o.w = v.w * P.x - P.y;
    } else {
        const float* vp = (const float*)&v;
        float* op = (float*)&o;
        #pragma unroll
        for (int j = 0; j < 4; ++j) {
            int btj = (e + j) / V;
            float4 P = params[btj];
            op[j] = vp[j] * P.x - P.y;
        }
    }
    out[idx] = o;
}

// ---------------------------------------------------------------------------
// Kernel 3: scatter the linear copy contribution:
//   out[bt, tok[b,s]] += (1-p[bt]) * attn[bt,s]
// Duplicate tokens merge correctly via atomic adds (term is linear in copy).
// ---------------------------------------------------------------------------
__global__ __launch_bounds__(256) void scatter_kernel(
    const int*   __restrict__ tokens,
    const float* __restrict__ attn,
    const float4* __restrict__ params,
    float* __restrict__ out)
{
    const int idx = blockIdx.x * 256 + threadIdx.x;   // < B*T*S
    const int bt  = idx / S_ENC;
    const int s   = idx - bt * S_ENC;
    const int b   = bt >> 7;
    const int tok = tokens[b * S_ENC + s];
    const float g = params[bt].z;                     // (1-p)
    atomicAdd(out + (size_t)bt * V + tok, g * attn[idx]);
}

extern "C" void kernel_launch(void* const* d_in, const int* in_sizes, int n_in,
                              void* d_out, int out_size, void* d_ws, size_t ws_size,
                              hipStream_t stream) {
    const int*   tokens  = (const int*)  d_in[0];
    const float* context = (const float*)d_in[1];
    const float* dec_in  = (const float*)d_in[2];
    const float* dec_out = (const float*)d_in[3];
    const float* vocab   = (const float*)d_in[4];
    const float* attn    = (const float*)d_in[5];
    // d_in[6] = encoder_outputs (unused by reference)
    const float* Wc = (const float*)d_in[7];
    const float* bc = (const float*)d_in[8];
    const float* Wo = (const float*)d_in[9];
    const float* bo = (const float*)d_in[10];
    const float* Wi = (const float*)d_in[11];
    const float* bi = (const float*)d_in[12];

    float*  out    = (float*) d_out;
    float4* params = (float4*)d_ws;   // B*T float4 = 16 KiB

    prep_kernel<<<B * T, 256, 0, stream>>>(tokens, context, dec_in, dec_out,
                                           attn, Wc, bc, Wo, bo, Wi, bi, params);

    const int total4 = (B * T * V) / 4;               // 12,865,792
    mix_kernel<<<total4 / 256, 256, 0, stream>>>(     // 50,257 blocks
        (const float4*)vocab, (const float4*)params, (float4*)out);

    scatter_kernel<<<(B * T * S_ENC) / 256, 256, 0, stream>>>(  // 1,600 blocks
        tokens, attn, params, out);
}

// Round 3
// 406.906 us; speedup vs baseline: 1.0985x; 1.0985x over previous
//
#include <hip/hip_runtime.h>
#include <math.h>

#define B 8
#define T 128
#define S_ENC 400
#define H 256
#define V 50257
#define HASH_SZ 1024   // power of 2, load factor 400/1024

typedef float vfloat4 __attribute__((ext_vector_type(4)));  // nontemporal-compatible

// ---------------------------------------------------------------------------
// Kernel 1: one block per (b,t). Computes:
//   p   = sigmoid(ctx.Wc + bc + dout.Wo + bo + din.Wi + bi)
//   lse = logsumexp over the copy_dist row (sparse: <=400 nonzeros after
//         duplicate-merge; remaining V-nnz entries are exactly 0)
// Dedup via LDS hash table (O(S) expected).
// Writes params[bt] = (p, (1-p)*lse, (1-p), 0)
// ---------------------------------------------------------------------------
__global__ __launch_bounds__(256) void prep_kernel(
    const int*   __restrict__ tokens,   // [B,S]
    const float* __restrict__ context,  // [B,T,H]
    const float* __restrict__ dec_in,   // [B,T,H]
    const float* __restrict__ dec_out,  // [B,T,H]
    const float* __restrict__ attn,     // [B,T,S]
    const float* __restrict__ Wc, const float* __restrict__ bc,
    const float* __restrict__ Wo, const float* __restrict__ bo,
    const float* __restrict__ Wi, const float* __restrict__ bi,
    float4* __restrict__ params)        // [B*T]
{
    __shared__ int   hkey[HASH_SZ];
    __shared__ float hval[HASH_SZ];
    __shared__ float s_pg[4];
    __shared__ float s_m[4];
    __shared__ int   s_n[4];
    __shared__ float s_se[4];
    __shared__ float s_mb;

    const int bt   = blockIdx.x;
    const int b    = bt >> 7;            // T = 128
    const int tid  = threadIdx.x;
    const int lane = tid & 63;
    const int wave = tid >> 6;

    #pragma unroll
    for (int i = tid; i < HASH_SZ; i += 256) {
        hkey[i] = -1;
        hval[i] = 0.0f;
    }
    __syncthreads();

    // p_gen partial: H == 256 == blockDim, one element per thread
    {
        float v = context[bt * H + tid] * Wc[tid]
                + dec_out[bt * H + tid] * Wo[tid]
                + dec_in [bt * H + tid] * Wi[tid];
        #pragma unroll
        for (int off = 32; off; off >>= 1) v += __shfl_down(v, off, 64);
        if (lane == 0) s_pg[wave] = v;
    }

    // hash-insert the scatter values (duplicate tokens merged by atomicAdd)
    for (int s = tid; s < S_ENC; s += 256) {
        const int   tk = tokens[b * S_ENC + s];
        const float a  = attn[bt * S_ENC + s];
        unsigned h = ((unsigned)tk * 2654435761u >> 16) & (HASH_SZ - 1);
        for (;;) {
            int prev = atomicCAS(&hkey[h], -1, tk);
            if (prev == -1 || prev == tk) { atomicAdd(&hval[h], a); break; }
            h = (h + 1) & (HASH_SZ - 1);
        }
    }
    __syncthreads();

    // max + nnz over merged sparse values
    {
        float m = 0.0f;   // zero entries exist (V >> nnz) so max >= 0
        int   n = 0;
        #pragma unroll
        for (int i = tid; i < HASH_SZ; i += 256) {
            if (hkey[i] != -1) { m = fmaxf(m, hval[i]); n++; }
        }
        #pragma unroll
        for (int off = 32; off; off >>= 1) {
            m  = fmaxf(m, __shfl_down(m, off, 64));
            n += __shfl_down(n, off, 64);
        }
        if (lane == 0) { s_m[wave] = m; s_n[wave] = n; }
    }
    __syncthreads();
    if (tid == 0) s_mb = fmaxf(fmaxf(s_m[0], s_m[1]), fmaxf(s_m[2], s_m[3]));
    __syncthreads();

    // sum of exp(val - m) over occupied slots
    {
        const float m = s_mb;
        float se = 0.0f;
        #pragma unroll
        for (int i = tid; i < HASH_SZ; i += 256) {
            if (hkey[i] != -1) se += expf(hval[i] - m);
        }
        #pragma unroll
        for (int off = 32; off; off >>= 1) se += __shfl_down(se, off, 64);
        if (lane == 0) s_se[wave] = se;
    }
    __syncthreads();

    if (tid == 0) {
        const float m   = s_mb;
        const int   nnz = s_n[0] + s_n[1] + s_n[2] + s_n[3];
        float se  = s_se[0] + s_se[1] + s_se[2] + s_se[3]
                  + (float)(V - nnz) * expf(-m);
        float lse = m + logf(se);
        float x   = s_pg[0] + s_pg[1] + s_pg[2] + s_pg[3]
                  + bc[0] + bo[0] + bi[0];
        float p   = 1.0f / (1.0f + expf(-x));
        float q   = 1.0f - p;
        params[bt] = make_float4(p, q * lse, q, 0.0f);
    }
}

// ---------------------------------------------------------------------------
// Kernel 2: streaming mix. out[e] = vocab[e]*p[bt] - (1-p[bt])*lse[bt]
// Nontemporal load/store (native clang vectors): pure streaming data, avoid
// write-allocate fetches and L2/L3 pollution. One float4 per thread.
// ---------------------------------------------------------------------------
__global__ __launch_bounds__(256) void mix_kernel(
    const vfloat4* __restrict__ vocab,
    const float4*  __restrict__ params,
    vfloat4* __restrict__ out)
{
    const int idx = blockIdx.x * 256 + threadIdx.x;   // < B*T*V/4
    const int e   = idx * 4;
    const int bt  = e / V;                            // magic-mul (V constexpr)
    const int rem = e - bt * V;

    vfloat4 v = __builtin_nontemporal_load(&vocab[idx]);
    vfloat4 o;
    if (rem + 4 <= V) {
        const float4 P = params[bt];
        o = v * P.x - P.y;
    } else {
        #pragma unroll
        for (int j = 0; j < 4; ++j) {
            int btj = (e + j) / V;
            float4 P = params[btj];
            o[j] = v[j] * P.x - P.y;
        }
    }
    __builtin_nontemporal_store(o, &out[idx]);
}

// ---------------------------------------------------------------------------
// Kernel 3: scatter the linear copy contribution:
//   out[bt, tok[b,s]] += (1-p[bt]) * attn[bt,s]
// Must run after mix (mix does plain stores to the same lines).
// ---------------------------------------------------------------------------
__global__ __launch_bounds__(256) void scatter_kernel(
    const int*   __restrict__ tokens,
    const float* __restrict__ attn,
    const float4* __restrict__ params,
    float* __restrict__ out)
{
    const int idx = blockIdx.x * 256 + threadIdx.x;   // < B*T*S
    const int bt  = idx / S_ENC;
    const int s   = idx - bt * S_ENC;
    const int b   = bt >> 7;
    const int tok = tokens[b * S_ENC + s];
    const float g = params[bt].z;                     // (1-p)
    atomicAdd(out + (size_t)bt * V + tok, g * attn[idx]);
}

extern "C" void kernel_launch(void* const* d_in, const int* in_sizes, int n_in,
                              void* d_out, int out_size, void* d_ws, size_t ws_size,
                              hipStream_t stream) {
    const int*   tokens  = (const int*)  d_in[0];
    const float* context = (const float*)d_in[1];
    const float* dec_in  = (const float*)d_in[2];
    const float* dec_out = (const float*)d_in[3];
    const float* vocab   = (const float*)d_in[4];
    const float* attn    = (const float*)d_in[5];
    // d_in[6] = encoder_outputs (unused by reference)
    const float* Wc = (const float*)d_in[7];
    const float* bc = (const float*)d_in[8];
    const float* Wo = (const float*)d_in[9];
    const float* bo = (const float*)d_in[10];
    const float* Wi = (const float*)d_in[11];
    const float* bi = (const float*)d_in[12];

    float*  out    = (float*) d_out;
    float4* params = (float4*)d_ws;   // B*T float4 = 16 KiB

    prep_kernel<<<B * T, 256, 0, stream>>>(tokens, context, dec_in, dec_out,
                                           attn, Wc, bc, Wo, bo, Wi, bi, params);

    const int total4 = (B * T * V) / 4;               // 12,865,792
    mix_kernel<<<total4 / 256, 256, 0, stream>>>(     // 50,257 blocks
        (const vfloat4*)vocab, (const float4*)params, (vfloat4*)out);

    scatter_kernel<<<(B * T * S_ENC) / 256, 256, 0, stream>>>(  // 1,600 blocks
        tokens, attn, params, out);
}